// Round 5
// baseline (137.786 us; speedup 1.0000x reference)
//
#include <hip/hip_runtime.h>

#define LN 4096
#define DN 150
#define NTB 5          // N-tiles (of 16) per gemm block; grid.y=2 covers 10 tiles = 160 cols
#define NPADB 80       // NTB*16
#define PPITCH 130     // LDS transpose pitch (elements): 4*130 mod 32 = 8 -> <=4-way conflicts

typedef __attribute__((ext_vector_type(8))) short bf16x8;
typedef __attribute__((ext_vector_type(4))) float f32x4;
typedef __attribute__((ext_vector_type(2))) float f32x2;

// round-to-nearest-even fp32 -> bf16 (finite inputs only)
__device__ __forceinline__ short f2bf(float f) {
    unsigned int u = __builtin_bit_cast(unsigned int, f);
    u = (u + 0x7FFFu + ((u >> 16) & 1u)) >> 16;
    return (short)u;
}

// h [4096][150] f32  ->  Ht [160][4096] bf16 (rows 150..159 zero)
__global__ __launch_bounds__(256) void k_transpose(const float* __restrict__ h,
                                                   unsigned short* __restrict__ Ht) {
    __shared__ float S[64][33];
    const int i0 = blockIdx.x * 64;
    const int d0 = blockIdx.y * 32;
    const int tid = threadIdx.x;
    for (int t = tid; t < 64 * 32; t += 256) {
        int ii = t >> 5, dd = t & 31;
        int d = d0 + dd;
        S[ii][dd] = (d < DN) ? h[(size_t)(i0 + ii) * DN + d] : 0.0f;
    }
    __syncthreads();
    for (int t = tid; t < 32 * 64; t += 256) {
        int dd = t >> 6, ii = t & 63;
        Ht[(size_t)(d0 + dd) * LN + i0 + ii] = (unsigned short)f2bf(S[ii][dd]);
    }
}

// One contiguous pass over adj: Abf[i][j] = bf16(adj[i][j][0]+adj[i][j][1]), AbfT[j][i] = same.
// 128x128 tile per block; LDS transpose for the AbfT side.
__global__ __launch_bounds__(256) void k_prep(const float* __restrict__ adj,
                                              unsigned short* __restrict__ Abf,
                                              unsigned short* __restrict__ AbfT) {
    __shared__ unsigned int S[(128 * PPITCH) / 2];  // bf16 elems packed as u32 pairs (33,280 B)
    const int i0 = blockIdx.x * 128, j0 = blockIdx.y * 128;
    const int t = threadIdx.x;
    const int rg = t >> 4;        // 0..15: row within 16-row group
    const int cc = (t & 15) * 8;  // col chunk of 8

    #pragma unroll
    for (int it = 0; it < 8; ++it) {
        int row = it * 16 + rg;
        size_t fbase = ((size_t)(i0 + row) * LN + (size_t)(j0 + cc)) * 2;  // float idx, 64B-aligned
        const f32x4* p = reinterpret_cast<const f32x4*>(adj + fbase);
        f32x4 v0 = p[0], v1 = p[1], v2 = p[2], v3 = p[3];
        bf16x8 a;
        a[0] = f2bf(v0.x + v0.y); a[1] = f2bf(v0.z + v0.w);
        a[2] = f2bf(v1.x + v1.y); a[3] = f2bf(v1.z + v1.w);
        a[4] = f2bf(v2.x + v2.y); a[5] = f2bf(v2.z + v2.w);
        a[6] = f2bf(v3.x + v3.y); a[7] = f2bf(v3.z + v3.w);
        *reinterpret_cast<bf16x8*>(Abf + (size_t)(i0 + row) * LN + j0 + cc) = a;
        int ebase = (row * PPITCH + cc) >> 1;  // u32 index (row*PPITCH+cc is even)
        #pragma unroll
        for (int q = 0; q < 4; ++q)
            S[ebase + q] = (unsigned int)(unsigned short)a[2 * q] |
                           ((unsigned int)(unsigned short)a[2 * q + 1] << 16);
    }
    __syncthreads();
    const unsigned short* Su = reinterpret_cast<const unsigned short*>(S);
    #pragma unroll
    for (int it = 0; it < 8; ++it) {
        int jl = it * 16 + rg;
        bf16x8 b;
        #pragma unroll
        for (int q = 0; q < 8; ++q)
            b[q] = (short)Su[(cc + q) * PPITCH + jl];
        *reinterpret_cast<bf16x8*>(AbfT + (size_t)(j0 + jl) * LN + i0 + cc) = b;
    }
}

// out[m0+r][d0+c] = sum_k A[m0+r][k] * Ht[d0+c][k]  — A is row-major bf16 (Abf or AbfT).
__global__ __launch_bounds__(256) void k_gemm_bf16(const unsigned short* __restrict__ A,
                                                   const unsigned short* __restrict__ Ht,
                                                   float* __restrict__ out) {
    const int tid  = threadIdx.x;
    const int lane = tid & 63;
    const int wave = tid >> 6;
    const int r = lane & 15;   // A row / B col / C col within 16-tile
    const int g = lane >> 4;   // k-group
    const int m0 = blockIdx.x * 16;
    const int t0 = blockIdx.y * NTB;   // first N-tile
    const int kbeg = wave * (LN / 4);  // waves split K into quarters

    const f32x4 zero = {0.f, 0.f, 0.f, 0.f};
    f32x4 acc[NTB];
    #pragma unroll
    for (int t = 0; t < NTB; ++t) acc[t] = zero;

    bf16x8 Aa, Ab, Ba[NTB], Bb[NTB];  // static-named pipeline buffers (rule #20)
    const size_t arow = (size_t)(m0 + r) * LN;

    auto loadA = [&](bf16x8& av, int s) {
        int k = kbeg + s * 32 + g * 8;
        av = *reinterpret_cast<const bf16x8*>(A + arow + k);
    };
    auto loadB = [&](bf16x8 (&bb)[NTB], int s) {
        int k = kbeg + s * 32 + g * 8;
        #pragma unroll
        for (int t = 0; t < NTB; ++t)
            bb[t] = *reinterpret_cast<const bf16x8*>(Ht + (size_t)((t0 + t) * 16 + r) * LN + k);
    };
    auto proc = [&](bf16x8& av, bf16x8 (&bb)[NTB]) {
        #pragma unroll
        for (int t = 0; t < NTB; ++t)
            acc[t] = __builtin_amdgcn_mfma_f32_16x16x32_bf16(av, bb[t], acc[t], 0, 0, 0);
    };

    // A depth-2, B depth-1 register pipeline; A-prefetch AFTER consume (round-3 proven order)
    loadA(Aa, 0);
    loadB(Ba, 0);
    loadA(Ab, 1);
    #pragma unroll
    for (int s = 0; s < 32; s += 2) {
        loadB(Bb, s + 1);
        proc(Aa, Ba);
        if (s + 2 < 32) loadA(Aa, s + 2);
        if (s + 2 < 32) loadB(Ba, s + 2);
        proc(Ab, Bb);
        if (s + 3 < 32) loadA(Ab, s + 3);
    }

    // cross-wave K reduction in LDS, then store
    __shared__ float buf[16 * NPADB];
    const int row4 = g * 4;
    for (int w4 = 0; w4 < 4; ++w4) {
        if (wave == w4) {
            #pragma unroll
            for (int t = 0; t < NTB; ++t) {
                #pragma unroll
                for (int q = 0; q < 4; ++q) {
                    int idx = (row4 + q) * NPADB + t * 16 + r;  // C: col=lane&15, row=(lane>>4)*4+q
                    if (w4 == 0) buf[idx] = acc[t][q];
                    else         buf[idx] += acc[t][q];
                }
            }
        }
        __syncthreads();
    }
    const int dbase = t0 * 16;
    for (int t2 = tid; t2 < 16 * NPADB; t2 += 256) {
        int row = t2 / NPADB, col = t2 % NPADB;
        int d = dbase + col;
        if (d < DN) out[(size_t)(m0 + row) * DN + d] = buf[row * NPADB + col];
    }
}

// ---------------- fallback (round-3 path) if workspace is too small ----------------
template <int TRANS>
__global__ __launch_bounds__(256) void k_gemm_direct(const float* __restrict__ adj,
                                                     const unsigned short* __restrict__ Ht,
                                                     float* __restrict__ out) {
    const int tid  = threadIdx.x;
    const int lane = tid & 63;
    const int wave = tid >> 6;
    const int r = lane & 15;
    const int g = lane >> 4;
    const int m0 = blockIdx.x * 16;
    const int kbeg = wave * (LN / 4);
    const f32x4 zero = {0.f, 0.f, 0.f, 0.f};
    f32x4 acc[10];
    #pragma unroll
    for (int t = 0; t < 10; ++t) acc[t] = zero;
    f32x4 Aa[4], Ab[4];
    f32x2 Aa2[8], Ab2[8];
    bf16x8 Ba[10], Bb[10];
    const f32x4* adj4 = reinterpret_cast<const f32x4*>(adj);
    const f32x2* adj2 = reinterpret_cast<const f32x2*>(adj);
    const size_t arow = (size_t)(m0 + r) * LN;
    auto loadA0 = [&](f32x4 (&ab)[4], int s) {
        int k = kbeg + s * 32 + g * 8;
        const f32x4* p = adj4 + ((arow + (size_t)k) >> 1);
        #pragma unroll
        for (int q = 0; q < 4; ++q) ab[q] = p[q];
    };
    auto loadA1 = [&](f32x2 (&ab)[8], int s) {
        int k = kbeg + s * 32 + g * 8;
        #pragma unroll
        for (int q = 0; q < 8; ++q) ab[q] = adj2[(size_t)(k + q) * LN + m0 + r];
    };
    auto loadB = [&](bf16x8 (&bb)[10], int s) {
        int k = kbeg + s * 32 + g * 8;
        #pragma unroll
        for (int t = 0; t < 10; ++t)
            bb[t] = *reinterpret_cast<const bf16x8*>(Ht + (size_t)(t * 16 + r) * LN + k);
    };
    auto proc = [&](f32x4 (&ab)[4], f32x2 (&ab2)[8], bf16x8 (&bb)[10]) {
        bf16x8 a;
        if (TRANS == 0) {
            #pragma unroll
            for (int q = 0; q < 4; ++q) {
                f32x4 v = ab[q];
                a[2 * q] = f2bf(v.x + v.y);
                a[2 * q + 1] = f2bf(v.z + v.w);
            }
        } else {
            #pragma unroll
            for (int q = 0; q < 8; ++q) { f32x2 v = ab2[q]; a[q] = f2bf(v.x + v.y); }
        }
        #pragma unroll
        for (int t = 0; t < 10; ++t)
            acc[t] = __builtin_amdgcn_mfma_f32_16x16x32_bf16(a, bb[t], acc[t], 0, 0, 0);
    };
    #define LOAD_A(BUF, S) do { if (TRANS == 0) loadA0(BUF, (S)); else loadA1(BUF##2, (S)); } while (0)
    LOAD_A(Aa, 0);
    loadB(Ba, 0);
    LOAD_A(Ab, 1);
    #pragma unroll
    for (int s = 0; s < 32; s += 2) {
        loadB(Bb, s + 1);
        proc(Aa, Aa2, Ba);
        if (s + 2 < 32) LOAD_A(Aa, s + 2);
        if (s + 2 < 32) loadB(Ba, s + 2);
        proc(Ab, Ab2, Bb);
        if (s + 3 < 32) LOAD_A(Ab, s + 3);
    }
    #undef LOAD_A
    __shared__ float buf[16 * 160];
    const int row4 = g * 4;
    for (int w4 = 0; w4 < 4; ++w4) {
        if (wave == w4) {
            #pragma unroll
            for (int t = 0; t < 10; ++t)
                #pragma unroll
                for (int q = 0; q < 4; ++q) {
                    int idx = (row4 + q) * 160 + t * 16 + r;
                    if (w4 == 0) buf[idx] = acc[t][q];
                    else         buf[idx] += acc[t][q];
                }
        }
        __syncthreads();
    }
    for (int t2 = tid; t2 < 16 * DN; t2 += 256) {
        int row = t2 / DN, col = t2 % DN;
        out[(size_t)(m0 + row) * DN + col] = buf[row * 160 + col];
    }
}

extern "C" void kernel_launch(void* const* d_in, const int* in_sizes, int n_in,
                              void* d_out, int out_size, void* d_ws, size_t ws_size,
                              hipStream_t stream) {
    const float* adj = (const float*)d_in[0];
    const float* h   = (const float*)d_in[1];
    float* out = (float*)d_out;
    char* ws = (char*)d_ws;

    unsigned short* Ht = (unsigned short*)ws;                       // 1.31 MB
    const size_t offAbf  = 2u << 20;                                // 2 MB
    const size_t offAbfT = offAbf + (size_t)LN * LN * 2;            // +32 MB
    const size_t need    = offAbfT + (size_t)LN * LN * 2;           // 66 MB total

    k_transpose<<<dim3(64, 5), 256, 0, stream>>>(h, Ht);

    if (ws_size >= need) {
        unsigned short* Abf  = (unsigned short*)(ws + offAbf);
        unsigned short* AbfT = (unsigned short*)(ws + offAbfT);
        k_prep<<<dim3(32, 32), 256, 0, stream>>>(adj, Abf, AbfT);
        // d_out layout: [h_in (L*D) | h_out (L*D)]
        k_gemm_bf16<<<dim3(256, 2), 256, 0, stream>>>(Abf,  Ht, out + (size_t)LN * DN); // h_out = A @ h
        k_gemm_bf16<<<dim3(256, 2), 256, 0, stream>>>(AbfT, Ht, out);                   // h_in  = A^T @ h
    } else {
        k_gemm_direct<0><<<256, 256, 0, stream>>>(adj, Ht, out + (size_t)LN * DN);
        k_gemm_direct<1><<<256, 256, 0, stream>>>(adj, Ht, out);
    }
}

// Round 6
// 130.443 us; speedup vs baseline: 1.0563x; 1.0563x over previous
//
#include <hip/hip_runtime.h>

#define LN 4096
#define DN 150
#define NTB 5          // N-tiles (of 16) per gemm block; grid.y=2 covers 10 tiles = 160 cols
#define NPADB 80       // NTB*16

typedef __attribute__((ext_vector_type(8))) short bf16x8;
typedef __attribute__((ext_vector_type(4))) float f32x4;
typedef __attribute__((ext_vector_type(2))) float f32x2;

// round-to-nearest-even fp32 -> bf16 (finite inputs only)
__device__ __forceinline__ short f2bf(float f) {
    unsigned int u = __builtin_bit_cast(unsigned int, f);
    u = (u + 0x7FFFu + ((u >> 16) & 1u)) >> 16;
    return (short)u;
}

// h [4096][150] f32  ->  Ht [160][4096] bf16 (rows 150..159 zero)
__global__ __launch_bounds__(256) void k_transpose(const float* __restrict__ h,
                                                   unsigned short* __restrict__ Ht) {
    __shared__ float S[64][33];
    const int i0 = blockIdx.x * 64;
    const int d0 = blockIdx.y * 32;
    const int tid = threadIdx.x;
    for (int t = tid; t < 64 * 32; t += 256) {
        int ii = t >> 5, dd = t & 31;
        int d = d0 + dd;
        S[ii][dd] = (d < DN) ? h[(size_t)(i0 + ii) * DN + d] : 0.0f;
    }
    __syncthreads();
    for (int t = tid; t < 32 * 64; t += 256) {
        int dd = t >> 6, ii = t & 63;
        Ht[(size_t)(d0 + dd) * LN + i0 + ii] = (unsigned short)f2bf(S[ii][dd]);
    }
}

// One contiguous pass over adj (128x128-pair tile per block):
//   Abf[i][j]  = bf16(adj[i][j][0]+adj[i][j][1])   (written straight from registers)
//   AbfT[j][i] = same, via XOR-swizzled u32 LDS tile (conflict-free both phases).
// Every global-read instruction is 64 lanes x 16B = 1KB fully contiguous (one adj row segment).
__global__ __launch_bounds__(256) void k_prep(const float* __restrict__ adj,
                                              unsigned short* __restrict__ Abf,
                                              unsigned short* __restrict__ AbfT) {
    __shared__ unsigned int S[128 * 64];  // u32-packed bf16 tile, 32 KB, XOR-swizzled
    const int i0 = blockIdx.x * 128, j0 = blockIdx.y * 128;
    const int tid = threadIdx.x;
    const int lane = tid & 63;
    const int wave = tid >> 6;

    // ---- phase 1: rows; one full row (1KB) per wave-instruction ----
    #pragma unroll
    for (int b = 0; b < 8; ++b) {
        f32x4 v[4];
        #pragma unroll
        for (int q = 0; q < 4; ++q) {
            int row = wave * 32 + b * 4 + q;
            v[q] = *reinterpret_cast<const f32x4*>(
                adj + ((size_t)(i0 + row) * LN + j0) * 2 + lane * 4);
        }
        #pragma unroll
        for (int q = 0; q < 4; ++q) {
            int row = wave * 32 + b * 4 + q;
            unsigned int u = (unsigned int)(unsigned short)f2bf(v[q].x + v[q].y) |
                             ((unsigned int)(unsigned short)f2bf(v[q].z + v[q].w) << 16);
            S[row * 64 + (lane ^ ((row >> 2) & 31))] = u;
            *reinterpret_cast<unsigned int*>(Abf + (size_t)(i0 + row) * LN + j0 + lane * 2) = u;
        }
    }
    __syncthreads();

    // ---- phase 2: transposed output; 16B/lane contiguous stores ----
    #pragma unroll
    for (int it = 0; it < 8; ++it) {
        int jl = wave * 32 + it * 4 + (lane >> 4);  // tile column -> AbfT row
        int w  = jl >> 1;
        int hi = jl & 1;
        int ib = (lane & 15) * 8;                   // 8-consecutive-i chunk
        unsigned int x[8];
        #pragma unroll
        for (int r = 0; r < 8; ++r) {
            int row = ib + r;
            x[r] = S[row * 64 + (w ^ ((row >> 2) & 31))];
        }
        bf16x8 o;
        #pragma unroll
        for (int r = 0; r < 8; ++r)
            o[r] = (short)(hi ? (x[r] >> 16) : (x[r] & 0xffffu));
        *reinterpret_cast<bf16x8*>(AbfT + (size_t)(j0 + jl) * LN + i0 + ib) = o;
    }
}

// out[m0+r][d0+c] = sum_k A[m0+r][k] * Ht[d0+c][k]  — A is row-major bf16 (Abf or AbfT).
__global__ __launch_bounds__(256) void k_gemm_bf16(const unsigned short* __restrict__ A,
                                                   const unsigned short* __restrict__ Ht,
                                                   float* __restrict__ out) {
    const int tid  = threadIdx.x;
    const int lane = tid & 63;
    const int wave = tid >> 6;
    const int r = lane & 15;   // A row / B col / C col within 16-tile
    const int g = lane >> 4;   // k-group
    const int m0 = blockIdx.x * 16;
    const int t0 = blockIdx.y * NTB;   // first N-tile
    const int kbeg = wave * (LN / 4);  // waves split K into quarters

    const f32x4 zero = {0.f, 0.f, 0.f, 0.f};
    f32x4 acc[NTB];
    #pragma unroll
    for (int t = 0; t < NTB; ++t) acc[t] = zero;

    bf16x8 Aa, Ab, Ba[NTB], Bb[NTB];  // static-named pipeline buffers (rule #20)
    const size_t arow = (size_t)(m0 + r) * LN;

    auto loadA = [&](bf16x8& av, int s) {
        int k = kbeg + s * 32 + g * 8;
        av = *reinterpret_cast<const bf16x8*>(A + arow + k);
    };
    auto loadB = [&](bf16x8 (&bb)[NTB], int s) {
        int k = kbeg + s * 32 + g * 8;
        #pragma unroll
        for (int t = 0; t < NTB; ++t)
            bb[t] = *reinterpret_cast<const bf16x8*>(Ht + (size_t)((t0 + t) * 16 + r) * LN + k);
    };
    auto proc = [&](bf16x8& av, bf16x8 (&bb)[NTB]) {
        #pragma unroll
        for (int t = 0; t < NTB; ++t)
            acc[t] = __builtin_amdgcn_mfma_f32_16x16x32_bf16(av, bb[t], acc[t], 0, 0, 0);
    };

    // A depth-2, B depth-1 register pipeline; A-prefetch AFTER consume (round-3 proven order)
    loadA(Aa, 0);
    loadB(Ba, 0);
    loadA(Ab, 1);
    #pragma unroll
    for (int s = 0; s < 32; s += 2) {
        loadB(Bb, s + 1);
        proc(Aa, Ba);
        if (s + 2 < 32) loadA(Aa, s + 2);
        if (s + 2 < 32) loadB(Ba, s + 2);
        proc(Ab, Bb);
        if (s + 3 < 32) loadA(Ab, s + 3);
    }

    // cross-wave K reduction in LDS, then store
    __shared__ float buf[16 * NPADB];
    const int row4 = g * 4;
    for (int w4 = 0; w4 < 4; ++w4) {
        if (wave == w4) {
            #pragma unroll
            for (int t = 0; t < NTB; ++t) {
                #pragma unroll
                for (int q = 0; q < 4; ++q) {
                    int idx = (row4 + q) * NPADB + t * 16 + r;  // C: col=lane&15, row=(lane>>4)*4+q
                    if (w4 == 0) buf[idx] = acc[t][q];
                    else         buf[idx] += acc[t][q];
                }
            }
        }
        __syncthreads();
    }
    const int dbase = t0 * 16;
    for (int t2 = tid; t2 < 16 * NPADB; t2 += 256) {
        int row = t2 / NPADB, col = t2 % NPADB;
        int d = dbase + col;
        if (d < DN) out[(size_t)(m0 + row) * DN + d] = buf[row * NPADB + col];
    }
}

// ---------------- fallback (round-3 path) if workspace is too small ----------------
template <int TRANS>
__global__ __launch_bounds__(256) void k_gemm_direct(const float* __restrict__ adj,
                                                     const unsigned short* __restrict__ Ht,
                                                     float* __restrict__ out) {
    const int tid  = threadIdx.x;
    const int lane = tid & 63;
    const int wave = tid >> 6;
    const int r = lane & 15;
    const int g = lane >> 4;
    const int m0 = blockIdx.x * 16;
    const int kbeg = wave * (LN / 4);
    const f32x4 zero = {0.f, 0.f, 0.f, 0.f};
    f32x4 acc[10];
    #pragma unroll
    for (int t = 0; t < 10; ++t) acc[t] = zero;
    f32x4 Aa[4], Ab[4];
    f32x2 Aa2[8], Ab2[8];
    bf16x8 Ba[10], Bb[10];
    const f32x4* adj4 = reinterpret_cast<const f32x4*>(adj);
    const f32x2* adj2 = reinterpret_cast<const f32x2*>(adj);
    const size_t arow = (size_t)(m0 + r) * LN;
    auto loadA0 = [&](f32x4 (&ab)[4], int s) {
        int k = kbeg + s * 32 + g * 8;
        const f32x4* p = adj4 + ((arow + (size_t)k) >> 1);
        #pragma unroll
        for (int q = 0; q < 4; ++q) ab[q] = p[q];
    };
    auto loadA1 = [&](f32x2 (&ab)[8], int s) {
        int k = kbeg + s * 32 + g * 8;
        #pragma unroll
        for (int q = 0; q < 8; ++q) ab[q] = adj2[(size_t)(k + q) * LN + m0 + r];
    };
    auto loadB = [&](bf16x8 (&bb)[10], int s) {
        int k = kbeg + s * 32 + g * 8;
        #pragma unroll
        for (int t = 0; t < 10; ++t)
            bb[t] = *reinterpret_cast<const bf16x8*>(Ht + (size_t)(t * 16 + r) * LN + k);
    };
    auto proc = [&](f32x4 (&ab)[4], f32x2 (&ab2)[8], bf16x8 (&bb)[10]) {
        bf16x8 a;
        if (TRANS == 0) {
            #pragma unroll
            for (int q = 0; q < 4; ++q) {
                f32x4 v = ab[q];
                a[2 * q] = f2bf(v.x + v.y);
                a[2 * q + 1] = f2bf(v.z + v.w);
            }
        } else {
            #pragma unroll
            for (int q = 0; q < 8; ++q) { f32x2 v = ab2[q]; a[q] = f2bf(v.x + v.y); }
        }
        #pragma unroll
        for (int t = 0; t < 10; ++t)
            acc[t] = __builtin_amdgcn_mfma_f32_16x16x32_bf16(a, bb[t], acc[t], 0, 0, 0);
    };
    #define LOAD_A(BUF, S) do { if (TRANS == 0) loadA0(BUF, (S)); else loadA1(BUF##2, (S)); } while (0)
    LOAD_A(Aa, 0);
    loadB(Ba, 0);
    LOAD_A(Ab, 1);
    #pragma unroll
    for (int s = 0; s < 32; s += 2) {
        loadB(Bb, s + 1);
        proc(Aa, Aa2, Ba);
        if (s + 2 < 32) LOAD_A(Aa, s + 2);
        if (s + 2 < 32) loadB(Ba, s + 2);
        proc(Ab, Ab2, Bb);
        if (s + 3 < 32) LOAD_A(Ab, s + 3);
    }
    #undef LOAD_A
    __shared__ float buf[16 * 160];
    const int row4 = g * 4;
    for (int w4 = 0; w4 < 4; ++w4) {
        if (wave == w4) {
            #pragma unroll
            for (int t = 0; t < 10; ++t)
                #pragma unroll
                for (int q = 0; q < 4; ++q) {
                    int idx = (row4 + q) * 160 + t * 16 + r;
                    if (w4 == 0) buf[idx] = acc[t][q];
                    else         buf[idx] += acc[t][q];
                }
        }
        __syncthreads();
    }
    for (int t2 = tid; t2 < 16 * DN; t2 += 256) {
        int row = t2 / DN, col = t2 % DN;
        out[(size_t)(m0 + row) * DN + col] = buf[row * 160 + col];
    }
}

extern "C" void kernel_launch(void* const* d_in, const int* in_sizes, int n_in,
                              void* d_out, int out_size, void* d_ws, size_t ws_size,
                              hipStream_t stream) {
    const float* adj = (const float*)d_in[0];
    const float* h   = (const float*)d_in[1];
    float* out = (float*)d_out;
    char* ws = (char*)d_ws;

    unsigned short* Ht = (unsigned short*)ws;                       // 1.31 MB
    const size_t offAbf  = 2u << 20;                                // 2 MB
    const size_t offAbfT = offAbf + (size_t)LN * LN * 2;            // +32 MB
    const size_t need    = offAbfT + (size_t)LN * LN * 2;           // 66 MB total

    k_transpose<<<dim3(64, 5), 256, 0, stream>>>(h, Ht);

    if (ws_size >= need) {
        unsigned short* Abf  = (unsigned short*)(ws + offAbf);
        unsigned short* AbfT = (unsigned short*)(ws + offAbfT);
        k_prep<<<dim3(32, 32), 256, 0, stream>>>(adj, Abf, AbfT);
        // d_out layout: [h_in (L*D) | h_out (L*D)]
        k_gemm_bf16<<<dim3(256, 2), 256, 0, stream>>>(Abf,  Ht, out + (size_t)LN * DN); // h_out = A @ h
        k_gemm_bf16<<<dim3(256, 2), 256, 0, stream>>>(AbfT, Ht, out);                   // h_in  = A^T @ h
    } else {
        k_gemm_direct<0><<<256, 256, 0, stream>>>(adj, Ht, out + (size_t)LN * DN);
        k_gemm_direct<1><<<256, 256, 0, stream>>>(adj, Ht, out);
    }
}

// Round 7
// 105.050 us; speedup vs baseline: 1.3116x; 1.2417x over previous
//
#include <hip/hip_runtime.h>

#define LN 4096
#define DN 150
#define NT 10          // d padded to 10 x 16 tiles
#define KSPLIT 4
#define KQ 1024        // k per block
#define NSS 4          // super-steps of 256 k

typedef __attribute__((ext_vector_type(8))) short bf16x8;
typedef __attribute__((ext_vector_type(4))) float f32x4;

// round-to-nearest-even fp32 -> bf16 (finite inputs only)
__device__ __forceinline__ unsigned short f2bf(float f) {
    unsigned int u = __builtin_bit_cast(unsigned int, f);
    u = (u + 0x7FFFu + ((u >> 16) & 1u)) >> 16;
    return (unsigned short)u;
}

// h [4096][150] f32  ->  Ht [160][4096] bf16 (rows 150..159 zero)
__global__ __launch_bounds__(256) void k_transpose(const float* __restrict__ h,
                                                   unsigned short* __restrict__ Ht) {
    __shared__ float S[64][33];
    const int i0 = blockIdx.x * 64;
    const int d0 = blockIdx.y * 32;
    const int tid = threadIdx.x;
    for (int t = tid; t < 64 * 32; t += 256) {
        int ii = t >> 5, dd = t & 31;
        int d = d0 + dd;
        S[ii][dd] = (d < DN) ? h[(size_t)(i0 + ii) * DN + d] : 0.0f;
    }
    __syncthreads();
    for (int t = tid; t < 32 * 64; t += 256) {
        int dd = t >> 6, ii = t & 63;
        Ht[(size_t)(d0 + dd) * LN + i0 + ii] = f2bf(S[ii][dd]);
    }
}

// TR=0 (h_out): out[m0+row][d] += sum_k bf16(adj[m][k][0]+adj[m][k][1]) * Hbf[k][d]
// TR=1 (h_in):  out[m0+row=j][d] += sum_i bf16(adj[i][j][0]+adj[i][j][1]) * Hbf[i][d]
// Output must be pre-zeroed; KSPLIT partial blocks combine via atomicAdd.
template <int TR>
__global__ __launch_bounds__(256, 2) void k_gemm(const float* __restrict__ adj,
                                                 const unsigned short* __restrict__ Ht,
                                                 float* __restrict__ out) {
    __shared__ unsigned short At[2][32 * 256];  // [row][256 k] bf16, XOR-swizzled, dbuf (32 KB)
    __shared__ float red[32][160];              // cross-wave reduce (20 KB)
    const int tid  = threadIdx.x;
    const int lane = tid & 63;
    const int wave = tid >> 6;
    const int r16  = lane & 15;  // A row / B col / C col within 16-tile
    const int g    = lane >> 4;  // k-group
    const int m0 = blockIdx.x * 32;
    const int kq = blockIdx.y * KQ;

    f32x4 acc[2][NT];
    #pragma unroll
    for (int mt = 0; mt < 2; ++mt)
        #pragma unroll
        for (int n = 0; n < NT; ++n) acc[mt][n] = (f32x4){0.f, 0.f, 0.f, 0.f};

    f32x4 sv[16];  // staging registers (issue-early / write-late)

    auto stage_load = [&](int ss) {
        if (TR == 0) {
            const int row = tid >> 7;    // 2 rows per round
            const int kk  = tid & 127;   // k-pair
            #pragma unroll
            for (int rr = 0; rr < 16; ++rr) {
                int rowr = rr * 2 + row;
                sv[rr] = *reinterpret_cast<const f32x4*>(
                    adj + ((size_t)(m0 + rowr) * LN + kq + ss * 256 + 2 * kk) * 2);
            }
        } else {
            const int iof = tid >> 4;    // 16 i-rows per round
            const int jp  = tid & 15;    // j-pair
            #pragma unroll
            for (int rr = 0; rr < 16; ++rr) {
                int il = rr * 16 + iof;
                sv[rr] = *reinterpret_cast<const f32x4*>(
                    adj + ((size_t)(kq + ss * 256 + il) * LN + m0 + jp * 2) * 2);
            }
        }
    };
    auto stage_write = [&](int buf) {
        if (TR == 0) {
            const int row = tid >> 7;
            const int kk  = tid & 127;
            #pragma unroll
            for (int rr = 0; rr < 16; ++rr) {
                int rowr = rr * 2 + row;
                unsigned int u = (unsigned int)f2bf(sv[rr].x + sv[rr].y) |
                                 ((unsigned int)f2bf(sv[rr].z + sv[rr].w) << 16);
                *reinterpret_cast<unsigned int*>(
                    &At[buf][rowr * 256 + ((2 * kk) ^ ((rowr & 15) << 3))]) = u;
            }
        } else {
            const int iof = tid >> 4;
            const int jA  = (tid & 15) * 2, jB = jA + 1;
            #pragma unroll
            for (int rr = 0; rr < 16; ++rr) {
                int k = rr * 16 + iof;
                At[buf][jA * 256 + (k ^ ((jA & 15) << 3))] = f2bf(sv[rr].x + sv[rr].y);
                At[buf][jB * 256 + (k ^ ((jB & 15) << 3))] = f2bf(sv[rr].z + sv[rr].w);
            }
        }
    };
    auto frag = [&](int buf, int mt, int s) {
        int row  = mt * 16 + r16;
        int kloc = wave * 64 + s * 32 + g * 8;  // wave owns k-slice of 64 per super-step
        return *reinterpret_cast<const bf16x8*>(&At[buf][row * 256 + (kloc ^ (r16 << 3))]);
    };
    auto loadB = [&](bf16x8 (&bb)[NT], int ss, int s) {
        int k = kq + ss * 256 + wave * 64 + s * 32 + g * 8;
        #pragma unroll
        for (int n = 0; n < NT; ++n)
            bb[n] = *reinterpret_cast<const bf16x8*>(Ht + (size_t)(n * 16 + r16) * LN + k);
    };

    stage_load(0);
    stage_write(0);
    __syncthreads();
    for (int ss = 0; ss < NSS; ++ss) {
        const int buf = ss & 1;
        if (ss + 1 < NSS) stage_load(ss + 1);  // issue next tile's loads under compute
        #pragma unroll
        for (int s = 0; s < 2; ++s) {
            bf16x8 B[NT];
            loadB(B, ss, s);
            bf16x8 a0 = frag(buf, 0, s);
            bf16x8 a1 = frag(buf, 1, s);
            #pragma unroll
            for (int n = 0; n < NT; ++n) {
                acc[0][n] = __builtin_amdgcn_mfma_f32_16x16x32_bf16(a0, B[n], acc[0][n], 0, 0, 0);
                acc[1][n] = __builtin_amdgcn_mfma_f32_16x16x32_bf16(a1, B[n], acc[1][n], 0, 0, 0);
            }
        }
        __syncthreads();                        // all waves done reading buf^1 (prev iter)
        if (ss + 1 < NSS) stage_write(buf ^ 1);
        __syncthreads();                        // writes visible before next iter's reads
    }

    // cross-wave K reduction (waves hold k-slices), then atomic combine of KSPLIT partials
    for (int w4 = 0; w4 < 4; ++w4) {
        if (wave == w4) {
            #pragma unroll
            for (int mt = 0; mt < 2; ++mt)
                #pragma unroll
                for (int n = 0; n < NT; ++n)
                    #pragma unroll
                    for (int q = 0; q < 4; ++q) {
                        int row = mt * 16 + g * 4 + q;  // C: col=lane&15, row=(lane>>4)*4+q
                        if (w4 == 0) red[row][n * 16 + r16]  = acc[mt][n][q];
                        else         red[row][n * 16 + r16] += acc[mt][n][q];
                    }
        }
        __syncthreads();
    }
    for (int t2 = tid; t2 < 32 * DN; t2 += 256) {
        int row = t2 / DN, col = t2 % DN;
        atomicAdd(&out[(size_t)(m0 + row) * DN + col], red[row][col]);
    }
}

extern "C" void kernel_launch(void* const* d_in, const int* in_sizes, int n_in,
                              void* d_out, int out_size, void* d_ws, size_t ws_size,
                              hipStream_t stream) {
    const float* adj = (const float*)d_in[0];
    const float* h   = (const float*)d_in[1];
    float* out = (float*)d_out;
    unsigned short* Ht = (unsigned short*)d_ws;  // 160*4096*2 = 1.31 MB scratch

    hipMemsetAsync(d_out, 0, (size_t)out_size * sizeof(float), stream);
    k_transpose<<<dim3(64, 5), 256, 0, stream>>>(h, Ht);
    // d_out layout: [h_in (L*D) | h_out (L*D)]
    k_gemm<0><<<dim3(128, KSPLIT), 256, 0, stream>>>(adj, Ht, out + (size_t)LN * DN); // h_out
    k_gemm<1><<<dim3(128, KSPLIT), 256, 0, stream>>>(adj, Ht, out);                   // h_in
}

// Round 8
// 104.655 us; speedup vs baseline: 1.3166x; 1.0038x over previous
//
#include <hip/hip_runtime.h>

#define LN 4096
#define DN 150
#define NT 10          // d padded to 10 x 16 tiles
#define KSPLIT 4
#define KQ 1024        // k per block
#define NSS 4          // super-steps of 256 k

typedef __attribute__((ext_vector_type(8))) short bf16x8;
typedef __attribute__((ext_vector_type(4))) float f32x4;

// round-to-nearest-even fp32 -> bf16 (finite inputs only)
__device__ __forceinline__ unsigned short f2bf(float f) {
    unsigned int u = __builtin_bit_cast(unsigned int, f);
    u = (u + 0x7FFFu + ((u >> 16) & 1u)) >> 16;
    return (unsigned short)u;
}

// zero d_out (the captured hipMemsetAsync fill ran at 64 GB/s / 76 us — do it ourselves)
__global__ __launch_bounds__(256) void k_zero(f32x4* __restrict__ p, int n4) {
    int i = blockIdx.x * 256 + threadIdx.x;
    if (i < n4) p[i] = (f32x4){0.f, 0.f, 0.f, 0.f};
}

// h [4096][150] f32  ->  Ht [160][4096] bf16 (rows 150..159 zero)
__global__ __launch_bounds__(256) void k_transpose(const float* __restrict__ h,
                                                   unsigned short* __restrict__ Ht) {
    __shared__ float S[64][33];
    const int i0 = blockIdx.x * 64;
    const int d0 = blockIdx.y * 32;
    const int tid = threadIdx.x;
    for (int t = tid; t < 64 * 32; t += 256) {
        int ii = t >> 5, dd = t & 31;
        int d = d0 + dd;
        S[ii][dd] = (d < DN) ? h[(size_t)(i0 + ii) * DN + d] : 0.0f;
    }
    __syncthreads();
    for (int t = tid; t < 32 * 64; t += 256) {
        int dd = t >> 6, ii = t & 63;
        Ht[(size_t)(d0 + dd) * LN + i0 + ii] = f2bf(S[ii][dd]);
    }
}

// TR=0 (h_out): out[m0+row][d] += sum_k bf16(adj[m][k][0]+adj[m][k][1]) * Hbf[k][d]
// TR=1 (h_in):  out[m0+row=j][d] += sum_i bf16(adj[i][j][0]+adj[i][j][1]) * Hbf[i][d]
// Output must be pre-zeroed; KSPLIT partial blocks combine via atomicAdd.
template <int TR>
__global__ __launch_bounds__(256, 2) void k_gemm(const float* __restrict__ adj,
                                                 const unsigned short* __restrict__ Ht,
                                                 float* __restrict__ out) {
    __shared__ unsigned short At[2][32 * 256];  // [row][256 k] bf16, XOR-swizzled, dbuf (32 KB)
    __shared__ float red[32][160];              // cross-wave reduce (20 KB)
    const int tid  = threadIdx.x;
    const int lane = tid & 63;
    const int wave = tid >> 6;
    const int r16  = lane & 15;  // A row / B col / C col within 16-tile
    const int g    = lane >> 4;  // k-group
    const int m0 = blockIdx.x * 32;
    const int kq = blockIdx.y * KQ;

    f32x4 acc[2][NT];
    #pragma unroll
    for (int mt = 0; mt < 2; ++mt)
        #pragma unroll
        for (int n = 0; n < NT; ++n) acc[mt][n] = (f32x4){0.f, 0.f, 0.f, 0.f};

    f32x4 sv[16];  // staging registers (issue-early / write-late)

    auto stage_load = [&](int ss) {
        if (TR == 0) {
            const int row = tid >> 7;    // 2 rows per round
            const int kk  = tid & 127;   // k-pair
            #pragma unroll
            for (int rr = 0; rr < 16; ++rr) {
                int rowr = rr * 2 + row;
                sv[rr] = *reinterpret_cast<const f32x4*>(
                    adj + ((size_t)(m0 + rowr) * LN + kq + ss * 256 + 2 * kk) * 2);
            }
        } else {
            const int iof = tid >> 4;    // 16 i-rows per round
            const int jp  = tid & 15;    // j-pair
            #pragma unroll
            for (int rr = 0; rr < 16; ++rr) {
                int il = rr * 16 + iof;
                sv[rr] = *reinterpret_cast<const f32x4*>(
                    adj + ((size_t)(kq + ss * 256 + il) * LN + m0 + jp * 2) * 2);
            }
        }
    };
    auto stage_write = [&](int buf) {
        if (TR == 0) {
            const int row = tid >> 7;
            const int kk  = tid & 127;
            #pragma unroll
            for (int rr = 0; rr < 16; ++rr) {
                int rowr = rr * 2 + row;
                unsigned int u = (unsigned int)f2bf(sv[rr].x + sv[rr].y) |
                                 ((unsigned int)f2bf(sv[rr].z + sv[rr].w) << 16);
                *reinterpret_cast<unsigned int*>(
                    &At[buf][rowr * 256 + ((2 * kk) ^ ((rowr & 15) << 3))]) = u;
            }
        } else {
            const int iof = tid >> 4;
            const int jA  = (tid & 15) * 2, jB = jA + 1;
            #pragma unroll
            for (int rr = 0; rr < 16; ++rr) {
                int k = rr * 16 + iof;
                At[buf][jA * 256 + (k ^ ((jA & 15) << 3))] = f2bf(sv[rr].x + sv[rr].y);
                At[buf][jB * 256 + (k ^ ((jB & 15) << 3))] = f2bf(sv[rr].z + sv[rr].w);
            }
        }
    };
    auto frag = [&](int buf, int mt, int s) {
        int row  = mt * 16 + r16;
        int kloc = wave * 64 + s * 32 + g * 8;  // wave owns k-slice of 64 per super-step
        return *reinterpret_cast<const bf16x8*>(&At[buf][row * 256 + (kloc ^ (r16 << 3))]);
    };
    auto loadB = [&](bf16x8 (&bb)[NT], int ss, int s) {
        int k = kq + ss * 256 + wave * 64 + s * 32 + g * 8;
        #pragma unroll
        for (int n = 0; n < NT; ++n)
            bb[n] = *reinterpret_cast<const bf16x8*>(Ht + (size_t)(n * 16 + r16) * LN + k);
    };

    stage_load(0);
    stage_write(0);
    __syncthreads();
    for (int ss = 0; ss < NSS; ++ss) {
        const int buf = ss & 1;
        if (ss + 1 < NSS) stage_load(ss + 1);  // issue next tile's loads under compute
        #pragma unroll
        for (int s = 0; s < 2; ++s) {
            bf16x8 B[NT];
            loadB(B, ss, s);
            bf16x8 a0 = frag(buf, 0, s);
            bf16x8 a1 = frag(buf, 1, s);
            #pragma unroll
            for (int n = 0; n < NT; ++n) {
                acc[0][n] = __builtin_amdgcn_mfma_f32_16x16x32_bf16(a0, B[n], acc[0][n], 0, 0, 0);
                acc[1][n] = __builtin_amdgcn_mfma_f32_16x16x32_bf16(a1, B[n], acc[1][n], 0, 0, 0);
            }
        }
        __syncthreads();                        // all waves done reading buf^1 (prev iter)
        if (ss + 1 < NSS) stage_write(buf ^ 1);
        __syncthreads();                        // writes visible before next iter's reads
    }

    // cross-wave K reduction (waves hold k-slices), then atomic combine of KSPLIT partials
    for (int w4 = 0; w4 < 4; ++w4) {
        if (wave == w4) {
            #pragma unroll
            for (int mt = 0; mt < 2; ++mt)
                #pragma unroll
                for (int n = 0; n < NT; ++n)
                    #pragma unroll
                    for (int q = 0; q < 4; ++q) {
                        int row = mt * 16 + g * 4 + q;  // C: col=lane&15, row=(lane>>4)*4+q
                        if (w4 == 0) red[row][n * 16 + r16]  = acc[mt][n][q];
                        else         red[row][n * 16 + r16] += acc[mt][n][q];
                    }
        }
        __syncthreads();
    }
    for (int t2 = tid; t2 < 32 * DN; t2 += 256) {
        int row = t2 / DN, col = t2 % DN;
        atomicAdd(&out[(size_t)(m0 + row) * DN + col], red[row][col]);
    }
}

extern "C" void kernel_launch(void* const* d_in, const int* in_sizes, int n_in,
                              void* d_out, int out_size, void* d_ws, size_t ws_size,
                              hipStream_t stream) {
    const float* adj = (const float*)d_in[0];
    const float* h   = (const float*)d_in[1];
    float* out = (float*)d_out;
    unsigned short* Ht = (unsigned short*)d_ws;  // 160*4096*2 = 1.31 MB scratch

    const int n4 = out_size / 4;  // out_size = 2*4096*150, divisible by 4
    k_zero<<<(n4 + 255) / 256, 256, 0, stream>>>((f32x4*)out, n4);
    k_transpose<<<dim3(64, 5), 256, 0, stream>>>(h, Ht);
    // d_out layout: [h_in (L*D) | h_out (L*D)]
    k_gemm<0><<<dim3(128, KSPLIT), 256, 0, stream>>>(adj, Ht, out + (size_t)LN * DN); // h_out
    k_gemm<1><<<dim3(128, KSPLIT), 256, 0, stream>>>(adj, Ht, out);                   // h_in
}